// Round 12
// baseline (1345.276 us; speedup 1.0000x reference)
//
#include <hip/hip_runtime.h>
#include <hip/hip_bf16.h>
#include <cstdint>
#include <cstddef>

#define NE  16
#define HD  1024
#define ID  4096
#define TPE 2048
#define TOKENS 32768

typedef __attribute__((ext_vector_type(8))) short short8;     // 8 bf16 (4 VGPRs)
typedef __attribute__((ext_vector_type(4))) float f32x4;      // MFMA acc
typedef __attribute__((ext_vector_type(4))) unsigned short u16x4;
typedef __attribute__((ext_vector_type(8))) unsigned short u16x8;

static __device__ __forceinline__ unsigned short f2b(float f) {
    __bf16 h = (__bf16)f;                       // RNE fp32->bf16
    return __builtin_bit_cast(unsigned short, h);
}

// wave-level async global->LDS, 16B/lane: LDS dest = uniform base + lane*16
// (linear). Swizzle applied on the GLOBAL source (rule #21).
#define GLOAD16(gsrc, ldsbase)                                                  \
    __builtin_amdgcn_global_load_lds(                                           \
        (const __attribute__((address_space(1))) unsigned int*)(gsrc),          \
        (__attribute__((address_space(3))) unsigned int*)(ldsbase), 16, 0, 0)

#define MFMA16(a, b, c) __builtin_amdgcn_mfma_f32_16x16x32_bf16((a), (b), (c), 0, 0, 0)

// ---------------------------------------------------------------------------
// Pre-pass 1: hs fp32 -> bf16 (linear)
// ---------------------------------------------------------------------------
__global__ void k_f2b(const float* __restrict__ src, unsigned short* __restrict__ dst, int n4)
{
    int i = blockIdx.x * blockDim.x + threadIdx.x;
    int stride = gridDim.x * blockDim.x;
    for (; i < n4; i += stride) {
        float4 v = *(const float4*)(src + (size_t)i * 4);
        u16x4 b = { f2b(v.x), f2b(v.y), f2b(v.z), f2b(v.w) };
        *(u16x4*)(dst + (size_t)i * 4) = b;
    }
}

// ---------------------------------------------------------------------------
// Pre-pass 2: weight convert+transpose (vectorized 4x4 blocks).
// ---------------------------------------------------------------------------
__global__ __launch_bounds__(256) void k_transpose(const float* __restrict__ src,
                                                   unsigned short* __restrict__ dst,
                                                   int K, int N, int e0)
{
    __shared__ unsigned short LT[64][72];
    const int t  = threadIdx.x;
    const int eL = blockIdx.z;
    const float* s = src + (size_t)(e0 + eL) * K * N
                         + (size_t)(blockIdx.y * 64) * N + blockIdx.x * 64;
    unsigned short* d = dst + (size_t)eL * N * K
                            + (size_t)(blockIdx.x * 64) * K + blockIdx.y * 64;

    const int ct = t & 15;
    const int rt = t >> 4;
    float4 v0 = *(const float4*)(s + (size_t)(rt * 4 + 0) * N + ct * 4);
    float4 v1 = *(const float4*)(s + (size_t)(rt * 4 + 1) * N + ct * 4);
    float4 v2 = *(const float4*)(s + (size_t)(rt * 4 + 2) * N + ct * 4);
    float4 v3 = *(const float4*)(s + (size_t)(rt * 4 + 3) * N + ct * 4);
    {
        u16x4 w0 = { f2b(v0.x), f2b(v1.x), f2b(v2.x), f2b(v3.x) };
        u16x4 w1 = { f2b(v0.y), f2b(v1.y), f2b(v2.y), f2b(v3.y) };
        u16x4 w2 = { f2b(v0.z), f2b(v1.z), f2b(v2.z), f2b(v3.z) };
        u16x4 w3 = { f2b(v0.w), f2b(v1.w), f2b(v2.w), f2b(v3.w) };
        *(u16x4*)&LT[ct * 4 + 0][rt * 4] = w0;
        *(u16x4*)&LT[ct * 4 + 1][rt * 4] = w1;
        *(u16x4*)&LT[ct * 4 + 2][rt * 4] = w2;
        *(u16x4*)&LT[ct * 4 + 3][rt * 4] = w3;
    }
    __syncthreads();
    #pragma unroll
    for (int i = 0; i < 2; ++i) {
        int n  = i * 32 + (t >> 3);
        int k8 = (t & 7) * 8;
        u16x8 v = *(const u16x8*)&LT[n][k8];
        *(u16x8*)(d + (size_t)n * K + k8) = v;
    }
}

// ---------------------------------------------------------------------------
// GEMM1 + SwiGLU. 128x128 tile, 4 waves (64x64 wave tile), LDS 64KB ->
// 2 blocks/CU: independent blocks desynchronize barrier drains (m114
// mechanism; m103 measured 912 TF for this geometry vs 864 for 256^2).
// Pipeline, swizzle, fragment & epilogue logic identical to R5.
// B rows: 4 groups of 32 cols, even=gate, odd=up.
// ---------------------------------------------------------------------------
__global__ __launch_bounds__(256) void k_gemm1(const unsigned short* __restrict__ hsB,
                                               const unsigned short* __restrict__ gupT,
                                               unsigned short* __restrict__ gated,
                                               int e0)
{
    __shared__ unsigned short As[2][128 * 64];
    __shared__ unsigned short Bs[2][128 * 64];
    const int NT = HD / 64;   // 16

    const int t    = threadIdx.x;
    const int lane = t & 63;
    const int w    = t >> 6;
    const int wr   = w >> 1;          // 0..1
    const int wc   = w & 1;           // 0..1
    const int eL   = blockIdx.z;
    const int e    = e0 + eL;
    const int n0g  = blockIdx.x * 64;    // gated col base (64/block)
    const int m0   = blockIdx.y * 128;

    const unsigned short* gA  = hsB  + (size_t)(e * TPE + m0) * HD;
    const unsigned short* gBt = gupT + (size_t)eL * (2 * ID) * HD;

    f32x4 acc[4][4];
    #pragma unroll
    for (int i = 0; i < 4; ++i)
        #pragma unroll
        for (int j = 0; j < 4; ++j)
            acc[i][j] = f32x4{0.f, 0.f, 0.f, 0.f};

    auto STAGE = [&](int buf, int kt) {            // 8 gloads
        #pragma unroll
        for (int i = 0; i < 4; ++i) {              // A: 128 rows x 64 k
            int idx = i * 256 + t;
            int row = idx >> 3, sl = idx & 7;
            GLOAD16(gA + (size_t)row * HD + kt * 64 + ((sl ^ (row & 7)) << 3),
                    &As[buf][(size_t)(i * 256 + (t & ~63)) * 8]);
        }
        #pragma unroll
        for (int i = 0; i < 4; ++i) {              // B: 128 rows (gate/up x32 groups)
            int idx = i * 256 + t;
            int c = idx >> 3, sl = idx & 7;
            int g = c >> 5;
            int grow = ((g & 1) ? ID : 0) + n0g + ((g >> 1) << 5) + (c & 31);
            GLOAD16(gBt + (size_t)grow * HD + kt * 64 + ((sl ^ (c & 7)) << 3),
                    &Bs[buf][(size_t)(i * 256 + (t & ~63)) * 8]);
        }
    };

    STAGE(0, 0);
    STAGE(1, 1);

    for (int kt = 0; kt < NT; ++kt) {
        const int cur = kt & 1;
        const unsigned short* Ab = &As[cur][0];
        const unsigned short* Bb = &Bs[cur][0];

        // ---- top wait: tile kt resident ----
        if (kt < NT - 1) { asm volatile("s_waitcnt vmcnt(8)" ::: "memory"); }
        else             { asm volatile("s_waitcnt vmcnt(0)" ::: "memory"); }
        __builtin_amdgcn_s_barrier();

        // ---- ks0 fragments + MFMAs (ks1 reads interleave under these) ----
        short8 av[4], bv[4];
        #pragma unroll
        for (int fm = 0; fm < 4; ++fm) {
            int row = wr * 64 + fm * 16 + (lane & 15);
            int sl  = (lane >> 4);
            av[fm] = *(const short8*)&Ab[row * 64 + ((sl ^ (row & 7)) << 3)];
        }
        #pragma unroll
        for (int fn = 0; fn < 4; ++fn) {
            int c  = wc * 64 + fn * 16 + (lane & 15);
            int sl = (lane >> 4);
            bv[fn] = *(const short8*)&Bb[c * 64 + ((sl ^ (c & 7)) << 3)];
        }
        __builtin_amdgcn_s_setprio(1);
        #pragma unroll
        for (int fm = 0; fm < 4; ++fm)
            #pragma unroll
            for (int fn = 0; fn < 4; ++fn)
                acc[fm][fn] = MFMA16(av[fm], bv[fn], acc[fm][fn]);
        __builtin_amdgcn_s_setprio(0);

        // ---- ks1 fragments ----
        short8 av1[4], bv1[4];
        #pragma unroll
        for (int fm = 0; fm < 4; ++fm) {
            int row = wr * 64 + fm * 16 + (lane & 15);
            int sl  = 4 + (lane >> 4);
            av1[fm] = *(const short8*)&Ab[row * 64 + ((sl ^ (row & 7)) << 3)];
        }
        #pragma unroll
        for (int fn = 0; fn < 4; ++fn) {
            int c  = wc * 64 + fn * 16 + (lane & 15);
            int sl = 4 + (lane >> 4);
            bv1[fn] = *(const short8*)&Bb[c * 64 + ((sl ^ (c & 7)) << 3)];
        }
        asm volatile("s_waitcnt lgkmcnt(0)" ::: "memory");
        __builtin_amdgcn_sched_barrier(0);
        __builtin_amdgcn_s_barrier();            // all waves done reading buf[cur]
        if (kt + 2 < NT)
            STAGE(cur, kt + 2);                  // overwrite freed buffer; NO wait here
        __builtin_amdgcn_s_setprio(1);
        #pragma unroll
        for (int fm = 0; fm < 4; ++fm)
            #pragma unroll
            for (int fn = 0; fn < 4; ++fn)
                acc[fm][fn] = MFMA16(av1[fm], bv1[fn], acc[fm][fn]);
        __builtin_amdgcn_s_setprio(0);
    }
    asm volatile("s_waitcnt vmcnt(0)" ::: "memory");   // drain DMAs before exit

    // ---- SwiGLU epilogue: fn (gate) pairs with fn+2 (up), same cols ----
    unsigned short* g0 = gated + ((size_t)eL * TPE + m0) * ID;
    const int rq = (lane >> 4) << 2;   // C/D: row=(lane>>4)*4+r, col=lane&15 (m89)
    const int cl = lane & 15;
    #pragma unroll
    for (int fm = 0; fm < 4; ++fm) {
        #pragma unroll
        for (int fp = 0; fp < 2; ++fp) {
            f32x4 g = acc[fm][fp];
            f32x4 u = acc[fm][fp + 2];
            #pragma unroll
            for (int r = 0; r < 4; ++r) {
                float gv  = g[r];
                float val = u[r] * gv / (1.0f + __expf(-gv));
                int row = wr * 64 + fm * 16 + rq + r;
                int col = n0g + wc * 32 + fp * 16 + cl;
                g0[(size_t)row * ID + col] = f2b(val);
            }
        }
    }
}

// ---------------------------------------------------------------------------
// GEMM2: gated bf16 @ dwnT bf16 -> out fp32. 128x128 tile, same pipeline.
// ---------------------------------------------------------------------------
__global__ __launch_bounds__(256) void k_gemm2(const unsigned short* __restrict__ gated,
                                               const unsigned short* __restrict__ dwnT,
                                               float* __restrict__ out,
                                               int e0)
{
    __shared__ unsigned short As[2][128 * 64];
    __shared__ unsigned short Bs[2][128 * 64];
    const int NT = ID / 64;   // 64

    const int t    = threadIdx.x;
    const int lane = t & 63;
    const int w    = t >> 6;
    const int wr   = w >> 1;
    const int wc   = w & 1;
    const int eL   = blockIdx.z;
    const int e    = e0 + eL;
    const int n0   = blockIdx.x * 128;
    const int m0   = blockIdx.y * 128;

    const unsigned short* gA  = gated + ((size_t)eL * TPE + m0) * ID;
    const unsigned short* gBt = dwnT  + (size_t)eL * HD * ID;

    f32x4 acc[4][4];
    #pragma unroll
    for (int i = 0; i < 4; ++i)
        #pragma unroll
        for (int j = 0; j < 4; ++j)
            acc[i][j] = f32x4{0.f, 0.f, 0.f, 0.f};

    auto STAGE = [&](int buf, int kt) {
        #pragma unroll
        for (int i = 0; i < 4; ++i) {
            int idx = i * 256 + t;
            int row = idx >> 3, sl = idx & 7;
            GLOAD16(gA + (size_t)row * ID + kt * 64 + ((sl ^ (row & 7)) << 3),
                    &As[buf][(size_t)(i * 256 + (t & ~63)) * 8]);
        }
        #pragma unroll
        for (int i = 0; i < 4; ++i) {
            int idx = i * 256 + t;
            int c = idx >> 3, sl = idx & 7;
            GLOAD16(gBt + (size_t)(n0 + c) * ID + kt * 64 + ((sl ^ (c & 7)) << 3),
                    &Bs[buf][(size_t)(i * 256 + (t & ~63)) * 8]);
        }
    };

    STAGE(0, 0);
    STAGE(1, 1);

    for (int kt = 0; kt < NT; ++kt) {
        const int cur = kt & 1;
        const unsigned short* Ab = &As[cur][0];
        const unsigned short* Bb = &Bs[cur][0];

        if (kt < NT - 1) { asm volatile("s_waitcnt vmcnt(8)" ::: "memory"); }
        else             { asm volatile("s_waitcnt vmcnt(0)" ::: "memory"); }
        __builtin_amdgcn_s_barrier();

        short8 av[4], bv[4];
        #pragma unroll
        for (int fm = 0; fm < 4; ++fm) {
            int row = wr * 64 + fm * 16 + (lane & 15);
            int sl  = (lane >> 4);
            av[fm] = *(const short8*)&Ab[row * 64 + ((sl ^ (row & 7)) << 3)];
        }
        #pragma unroll
        for (int fn = 0; fn < 4; ++fn) {
            int c  = wc * 64 + fn * 16 + (lane & 15);
            int sl = (lane >> 4);
            bv[fn] = *(const short8*)&Bb[c * 64 + ((sl ^ (c & 7)) << 3)];
        }
        __builtin_amdgcn_s_setprio(1);
        #pragma unroll
        for (int fm = 0; fm < 4; ++fm)
            #pragma unroll
            for (int fn = 0; fn < 4; ++fn)
                acc[fm][fn] = MFMA16(av[fm], bv[fn], acc[fm][fn]);
        __builtin_amdgcn_s_setprio(0);

        short8 av1[4], bv1[4];
        #pragma unroll
        for (int fm = 0; fm < 4; ++fm) {
            int row = wr * 64 + fm * 16 + (lane & 15);
            int sl  = 4 + (lane >> 4);
            av1[fm] = *(const short8*)&Ab[row * 64 + ((sl ^ (row & 7)) << 3)];
        }
        #pragma unroll
        for (int fn = 0; fn < 4; ++fn) {
            int c  = wc * 64 + fn * 16 + (lane & 15);
            int sl = 4 + (lane >> 4);
            bv1[fn] = *(const short8*)&Bb[c * 64 + ((sl ^ (c & 7)) << 3)];
        }
        asm volatile("s_waitcnt lgkmcnt(0)" ::: "memory");
        __builtin_amdgcn_sched_barrier(0);
        __builtin_amdgcn_s_barrier();
        if (kt + 2 < NT)
            STAGE(cur, kt + 2);
        __builtin_amdgcn_s_setprio(1);
        #pragma unroll
        for (int fm = 0; fm < 4; ++fm)
            #pragma unroll
            for (int fn = 0; fn < 4; ++fn)
                acc[fm][fn] = MFMA16(av1[fm], bv1[fn], acc[fm][fn]);
        __builtin_amdgcn_s_setprio(0);
    }
    asm volatile("s_waitcnt vmcnt(0)" ::: "memory");

    float* o0 = out + (size_t)(e * TPE + m0) * HD;
    const int rq = (lane >> 4) << 2;
    const int cl = lane & 15;
    #pragma unroll
    for (int fm = 0; fm < 4; ++fm) {
        #pragma unroll
        for (int fn = 0; fn < 4; ++fn) {
            #pragma unroll
            for (int r = 0; r < 4; ++r) {
                int row = wr * 64 + fm * 16 + rq + r;
                int col = n0 + wc * 64 + fn * 16 + cl;
                o0[(size_t)row * HD + col] = acc[fm][fn][r];
            }
        }
    }
}

extern "C" void kernel_launch(void* const* d_in, const int* in_sizes, int n_in,
                              void* d_out, int out_size, void* d_ws, size_t ws_size,
                              hipStream_t stream)
{
    (void)in_sizes; (void)n_in; (void)out_size;
    const float* hs  = (const float*)d_in[0];
    const float* gup = (const float*)d_in[1];
    const float* dwn = (const float*)d_in[2];
    float* out = (float*)d_out;

    const size_t SZ_HSB   = (size_t)TOKENS * HD * 2;          // 67.1 MB
    const size_t SZ_GUPT  = (size_t)2 * ID * HD * 2;          // 16.78 MB / expert
    const size_t SZ_DWNT  = (size_t)HD * ID * 2;              //  8.39 MB / expert
    const size_t SZ_GATED = (size_t)TPE * ID * 2;             // 16.78 MB / expert
    const size_t perExp   = SZ_GUPT + SZ_DWNT + SZ_GATED;     // 41.94 MB

    int G = (ws_size > SZ_HSB) ? (int)((ws_size - SZ_HSB) / perExp) : 1;
    if (G < 1) G = 1;
    if (G > NE) G = NE;

    unsigned short* hsB   = (unsigned short*)d_ws;
    unsigned short* gupT  = (unsigned short*)((char*)d_ws + SZ_HSB);
    unsigned short* dwnT  = (unsigned short*)((char*)d_ws + SZ_HSB + (size_t)G * SZ_GUPT);
    unsigned short* gated = (unsigned short*)((char*)d_ws + SZ_HSB + (size_t)G * (SZ_GUPT + SZ_DWNT));

    k_f2b<<<2048, 256, 0, stream>>>(hs, hsB, TOKENS * HD / 4);

    for (int e0 = 0; e0 < NE; e0 += G) {
        int ne = NE - e0;
        if (ne > G) ne = G;
        k_transpose<<<dim3((2 * ID) / 64, HD / 64, ne), 256, 0, stream>>>(gup, gupT, HD, 2 * ID, e0);
        k_transpose<<<dim3(HD / 64, ID / 64, ne), 256, 0, stream>>>(dwn, dwnT, ID, HD, e0);
        k_gemm1<<<dim3(ID / 64, TPE / 128, ne), 256, 0, stream>>>(hsB, gupT, gated, e0);
        k_gemm2<<<dim3(HD / 128, TPE / 128, ne), 256, 0, stream>>>(gated, dwnT, out, e0);
    }
}

// Round 13
// 1150.044 us; speedup vs baseline: 1.1698x; 1.1698x over previous
//
#include <hip/hip_runtime.h>
#include <hip/hip_bf16.h>
#include <cstdint>
#include <cstddef>

#define NE  16
#define HD  1024
#define ID  4096
#define TPE 2048
#define TOKENS 32768

typedef __attribute__((ext_vector_type(8))) short short8;     // 8 bf16 (4 VGPRs)
typedef __attribute__((ext_vector_type(4))) float f32x4;      // MFMA acc
typedef __attribute__((ext_vector_type(4))) unsigned short u16x4;
typedef __attribute__((ext_vector_type(8))) unsigned short u16x8;

static __device__ __forceinline__ unsigned short f2b(float f) {
    __bf16 h = (__bf16)f;                       // RNE fp32->bf16
    return __builtin_bit_cast(unsigned short, h);
}

// wave-level async global->LDS, 16B/lane: LDS dest = uniform base + lane*16
// (linear). Swizzle applied on the GLOBAL source (rule #21).
#define GLOAD16(gsrc, ldsbase)                                                  \
    __builtin_amdgcn_global_load_lds(                                           \
        (const __attribute__((address_space(1))) unsigned int*)(gsrc),          \
        (__attribute__((address_space(3))) unsigned int*)(ldsbase), 16, 0, 0)

#define MFMA16(a, b, c) __builtin_amdgcn_mfma_f32_16x16x32_bf16((a), (b), (c), 0, 0, 0)

// ---------------------------------------------------------------------------
// Pre-pass 1: hs fp32 -> bf16 (linear)
// ---------------------------------------------------------------------------
__global__ void k_f2b(const float* __restrict__ src, unsigned short* __restrict__ dst, int n4)
{
    int i = blockIdx.x * blockDim.x + threadIdx.x;
    int stride = gridDim.x * blockDim.x;
    for (; i < n4; i += stride) {
        float4 v = *(const float4*)(src + (size_t)i * 4);
        u16x4 b = { f2b(v.x), f2b(v.y), f2b(v.z), f2b(v.w) };
        *(u16x4*)(dst + (size_t)i * 4) = b;
    }
}

// ---------------------------------------------------------------------------
// Pre-pass 2: weight convert+transpose (vectorized 4x4 blocks).
// ---------------------------------------------------------------------------
__global__ __launch_bounds__(256) void k_transpose(const float* __restrict__ src,
                                                   unsigned short* __restrict__ dst,
                                                   int K, int N, int e0)
{
    __shared__ unsigned short LT[64][72];
    const int t  = threadIdx.x;
    const int eL = blockIdx.z;
    const float* s = src + (size_t)(e0 + eL) * K * N
                         + (size_t)(blockIdx.y * 64) * N + blockIdx.x * 64;
    unsigned short* d = dst + (size_t)eL * N * K
                            + (size_t)(blockIdx.x * 64) * K + blockIdx.y * 64;

    const int ct = t & 15;
    const int rt = t >> 4;
    float4 v0 = *(const float4*)(s + (size_t)(rt * 4 + 0) * N + ct * 4);
    float4 v1 = *(const float4*)(s + (size_t)(rt * 4 + 1) * N + ct * 4);
    float4 v2 = *(const float4*)(s + (size_t)(rt * 4 + 2) * N + ct * 4);
    float4 v3 = *(const float4*)(s + (size_t)(rt * 4 + 3) * N + ct * 4);
    {
        u16x4 w0 = { f2b(v0.x), f2b(v1.x), f2b(v2.x), f2b(v3.x) };
        u16x4 w1 = { f2b(v0.y), f2b(v1.y), f2b(v2.y), f2b(v3.y) };
        u16x4 w2 = { f2b(v0.z), f2b(v1.z), f2b(v2.z), f2b(v3.z) };
        u16x4 w3 = { f2b(v0.w), f2b(v1.w), f2b(v2.w), f2b(v3.w) };
        *(u16x4*)&LT[ct * 4 + 0][rt * 4] = w0;
        *(u16x4*)&LT[ct * 4 + 1][rt * 4] = w1;
        *(u16x4*)&LT[ct * 4 + 2][rt * 4] = w2;
        *(u16x4*)&LT[ct * 4 + 3][rt * 4] = w3;
    }
    __syncthreads();
    #pragma unroll
    for (int i = 0; i < 2; ++i) {
        int n  = i * 32 + (t >> 3);
        int k8 = (t & 7) * 8;
        u16x8 v = *(const u16x8*)&LT[n][k8];
        *(u16x8*)(d + (size_t)n * K + k8) = v;
    }
}

// ---------------------------------------------------------------------------
// GEMM1 + SwiGLU, 256x256 tile, 8 waves, counted-vmcnt double-buffer.
// Best verified configuration (R5/R11: 864 TF, 0 bank conflicts).
// Per kt: {vmcnt(8); barrier} [tile kt resident, staged >=1.5 iters ago] ->
// ks0 frags+MFMA (ks1 reads slide under) -> {lgkm(0); barrier} [buf released]
// -> STAGE(kt+2), no wait -> ks1 MFMA. Never vmcnt(0) in steady state.
// 16x16x32 MFMA: the only fragment shape whose 16-row-granular ds_read_b128
// is conflict-free under the global_load_lds linear-dest constraint.
// ---------------------------------------------------------------------------
__global__ __launch_bounds__(512, 2) void k_gemm1(const unsigned short* __restrict__ hsB,
                                                  const unsigned short* __restrict__ gupT,
                                                  unsigned short* __restrict__ gated,
                                                  int e0)
{
    __shared__ unsigned short As[2][256 * 64];
    __shared__ unsigned short Bs[2][256 * 64];
    const int NT = HD / 64;   // 16

    const int t    = threadIdx.x;
    const int lane = t & 63;
    const int w    = t >> 6;
    const int wr   = w >> 2;          // 0..1
    const int wc   = w & 3;           // 0..3
    const int eL   = blockIdx.z;
    const int e    = e0 + eL;
    const int n0g  = blockIdx.x * 128;   // gated col base
    const int m0   = blockIdx.y * 256;

    const unsigned short* gA  = hsB  + (size_t)(e * TPE + m0) * HD;
    const unsigned short* gBt = gupT + (size_t)eL * (2 * ID) * HD;

    f32x4 acc[8][4];
    #pragma unroll
    for (int i = 0; i < 8; ++i)
        #pragma unroll
        for (int j = 0; j < 4; ++j)
            acc[i][j] = f32x4{0.f, 0.f, 0.f, 0.f};

    auto STAGE = [&](int buf, int kt) {
        #pragma unroll
        for (int i = 0; i < 4; ++i) {              // A: 256 rows x 64 k
            int idx = i * 512 + t;
            int row = idx >> 3, sl = idx & 7;
            GLOAD16(gA + (size_t)row * HD + kt * 64 + ((sl ^ (row & 7)) << 3),
                    &As[buf][(size_t)(i * 512 + (t & ~63)) * 8]);
        }
        #pragma unroll
        for (int i = 0; i < 4; ++i) {              // B: 256 rows (gate/up x32 groups)
            int idx = i * 512 + t;
            int c = idx >> 3, sl = idx & 7;
            int g = c >> 5;
            int grow = ((g & 1) ? ID : 0) + n0g + ((g >> 1) << 5) + (c & 31);
            GLOAD16(gBt + (size_t)grow * HD + kt * 64 + ((sl ^ (c & 7)) << 3),
                    &Bs[buf][(size_t)(i * 512 + (t & ~63)) * 8]);
        }
    };

    STAGE(0, 0);
    STAGE(1, 1);

    for (int kt = 0; kt < NT; ++kt) {
        const int cur = kt & 1;
        const unsigned short* Ab = &As[cur][0];
        const unsigned short* Bb = &Bs[cur][0];

        // ---- top wait: tile kt resident ----
        if (kt < NT - 1) { asm volatile("s_waitcnt vmcnt(8)" ::: "memory"); }
        else             { asm volatile("s_waitcnt vmcnt(0)" ::: "memory"); }
        __builtin_amdgcn_s_barrier();

        // ---- ks0 fragments + MFMAs (ks1 reads interleave under these) ----
        short8 av[8], bv[4];
        #pragma unroll
        for (int fm = 0; fm < 8; ++fm) {
            int row = wr * 128 + fm * 16 + (lane & 15);
            int sl  = (lane >> 4);
            av[fm] = *(const short8*)&Ab[row * 64 + ((sl ^ (row & 7)) << 3)];
        }
        #pragma unroll
        for (int fn = 0; fn < 4; ++fn) {
            int c  = wc * 64 + fn * 16 + (lane & 15);
            int sl = (lane >> 4);
            bv[fn] = *(const short8*)&Bb[c * 64 + ((sl ^ (c & 7)) << 3)];
        }
        __builtin_amdgcn_s_setprio(1);
        #pragma unroll
        for (int fm = 0; fm < 8; ++fm)
            #pragma unroll
            for (int fn = 0; fn < 4; ++fn)
                acc[fm][fn] = MFMA16(av[fm], bv[fn], acc[fm][fn]);
        __builtin_amdgcn_s_setprio(0);

        // ---- ks1 fragments ----
        short8 av1[8], bv1[4];
        #pragma unroll
        for (int fm = 0; fm < 8; ++fm) {
            int row = wr * 128 + fm * 16 + (lane & 15);
            int sl  = 4 + (lane >> 4);
            av1[fm] = *(const short8*)&Ab[row * 64 + ((sl ^ (row & 7)) << 3)];
        }
        #pragma unroll
        for (int fn = 0; fn < 4; ++fn) {
            int c  = wc * 64 + fn * 16 + (lane & 15);
            int sl = 4 + (lane >> 4);
            bv1[fn] = *(const short8*)&Bb[c * 64 + ((sl ^ (c & 7)) << 3)];
        }
        asm volatile("s_waitcnt lgkmcnt(0)" ::: "memory");
        __builtin_amdgcn_sched_barrier(0);
        __builtin_amdgcn_s_barrier();            // all waves done reading buf[cur]
        if (kt + 2 < NT)
            STAGE(cur, kt + 2);                  // overwrite freed buffer; NO wait here
        __builtin_amdgcn_s_setprio(1);
        #pragma unroll
        for (int fm = 0; fm < 8; ++fm)
            #pragma unroll
            for (int fn = 0; fn < 4; ++fn)
                acc[fm][fn] = MFMA16(av1[fm], bv1[fn], acc[fm][fn]);
        __builtin_amdgcn_s_setprio(0);
    }
    asm volatile("s_waitcnt vmcnt(0)" ::: "memory");   // drain DMAs before exit

    // ---- SwiGLU epilogue: fn (gate) pairs with fn+2 (up), same cols ----
    unsigned short* g0 = gated + ((size_t)eL * TPE + m0) * ID;
    const int rq = (lane >> 4) << 2;   // C/D: row=(lane>>4)*4+r, col=lane&15 (m89)
    const int cl = lane & 15;
    #pragma unroll
    for (int fm = 0; fm < 8; ++fm) {
        #pragma unroll
        for (int fp = 0; fp < 2; ++fp) {
            f32x4 g = acc[fm][fp];
            f32x4 u = acc[fm][fp + 2];
            #pragma unroll
            for (int r = 0; r < 4; ++r) {
                float gv  = g[r];
                float val = u[r] * gv / (1.0f + __expf(-gv));
                int row = wr * 128 + fm * 16 + rq + r;
                int col = n0g + wc * 32 + fp * 16 + cl;
                g0[(size_t)row * ID + col] = f2b(val);
            }
        }
    }
}

// ---------------------------------------------------------------------------
// GEMM2: gated bf16 @ dwnT bf16 -> out fp32. Same pipeline.
// ---------------------------------------------------------------------------
__global__ __launch_bounds__(512, 2) void k_gemm2(const unsigned short* __restrict__ gated,
                                                  const unsigned short* __restrict__ dwnT,
                                                  float* __restrict__ out,
                                                  int e0)
{
    __shared__ unsigned short As[2][256 * 64];
    __shared__ unsigned short Bs[2][256 * 64];
    const int NT = ID / 64;   // 64

    const int t    = threadIdx.x;
    const int lane = t & 63;
    const int w    = t >> 6;
    const int wr   = w >> 2;
    const int wc   = w & 3;
    const int eL   = blockIdx.z;
    const int e    = e0 + eL;
    const int n0   = blockIdx.x * 256;
    const int m0   = blockIdx.y * 256;

    const unsigned short* gA  = gated + ((size_t)eL * TPE + m0) * ID;
    const unsigned short* gBt = dwnT  + (size_t)eL * HD * ID;

    f32x4 acc[8][4];
    #pragma unroll
    for (int i = 0; i < 8; ++i)
        #pragma unroll
        for (int j = 0; j < 4; ++j)
            acc[i][j] = f32x4{0.f, 0.f, 0.f, 0.f};

    auto STAGE = [&](int buf, int kt) {
        #pragma unroll
        for (int i = 0; i < 4; ++i) {
            int idx = i * 512 + t;
            int row = idx >> 3, sl = idx & 7;
            GLOAD16(gA + (size_t)row * ID + kt * 64 + ((sl ^ (row & 7)) << 3),
                    &As[buf][(size_t)(i * 512 + (t & ~63)) * 8]);
        }
        #pragma unroll
        for (int i = 0; i < 4; ++i) {
            int idx = i * 512 + t;
            int c = idx >> 3, sl = idx & 7;
            GLOAD16(gBt + (size_t)(n0 + c) * ID + kt * 64 + ((sl ^ (c & 7)) << 3),
                    &Bs[buf][(size_t)(i * 512 + (t & ~63)) * 8]);
        }
    };

    STAGE(0, 0);
    STAGE(1, 1);

    for (int kt = 0; kt < NT; ++kt) {
        const int cur = kt & 1;
        const unsigned short* Ab = &As[cur][0];
        const unsigned short* Bb = &Bs[cur][0];

        if (kt < NT - 1) { asm volatile("s_waitcnt vmcnt(8)" ::: "memory"); }
        else             { asm volatile("s_waitcnt vmcnt(0)" ::: "memory"); }
        __builtin_amdgcn_s_barrier();

        short8 av[8], bv[4];
        #pragma unroll
        for (int fm = 0; fm < 8; ++fm) {
            int row = wr * 128 + fm * 16 + (lane & 15);
            int sl  = (lane >> 4);
            av[fm] = *(const short8*)&Ab[row * 64 + ((sl ^ (row & 7)) << 3)];
        }
        #pragma unroll
        for (int fn = 0; fn < 4; ++fn) {
            int c  = wc * 64 + fn * 16 + (lane & 15);
            int sl = (lane >> 4);
            bv[fn] = *(const short8*)&Bb[c * 64 + ((sl ^ (c & 7)) << 3)];
        }
        __builtin_amdgcn_s_setprio(1);
        #pragma unroll
        for (int fm = 0; fm < 8; ++fm)
            #pragma unroll
            for (int fn = 0; fn < 4; ++fn)
                acc[fm][fn] = MFMA16(av[fm], bv[fn], acc[fm][fn]);
        __builtin_amdgcn_s_setprio(0);

        short8 av1[8], bv1[4];
        #pragma unroll
        for (int fm = 0; fm < 8; ++fm) {
            int row = wr * 128 + fm * 16 + (lane & 15);
            int sl  = 4 + (lane >> 4);
            av1[fm] = *(const short8*)&Ab[row * 64 + ((sl ^ (row & 7)) << 3)];
        }
        #pragma unroll
        for (int fn = 0; fn < 4; ++fn) {
            int c  = wc * 64 + fn * 16 + (lane & 15);
            int sl = 4 + (lane >> 4);
            bv1[fn] = *(const short8*)&Bb[c * 64 + ((sl ^ (c & 7)) << 3)];
        }
        asm volatile("s_waitcnt lgkmcnt(0)" ::: "memory");
        __builtin_amdgcn_sched_barrier(0);
        __builtin_amdgcn_s_barrier();
        if (kt + 2 < NT)
            STAGE(cur, kt + 2);
        __builtin_amdgcn_s_setprio(1);
        #pragma unroll
        for (int fm = 0; fm < 8; ++fm)
            #pragma unroll
            for (int fn = 0; fn < 4; ++fn)
                acc[fm][fn] = MFMA16(av1[fm], bv1[fn], acc[fm][fn]);
        __builtin_amdgcn_s_setprio(0);
    }
    asm volatile("s_waitcnt vmcnt(0)" ::: "memory");

    float* o0 = out + (size_t)(e * TPE + m0) * HD;
    const int rq = (lane >> 4) << 2;
    const int cl = lane & 15;
    #pragma unroll
    for (int fm = 0; fm < 8; ++fm) {
        #pragma unroll
        for (int fn = 0; fn < 4; ++fn) {
            #pragma unroll
            for (int r = 0; r < 4; ++r) {
                int row = wr * 128 + fm * 16 + rq + r;
                int col = n0 + wc * 64 + fn * 16 + cl;
                o0[(size_t)row * HD + col] = acc[fm][fn][r];
            }
        }
    }
}

extern "C" void kernel_launch(void* const* d_in, const int* in_sizes, int n_in,
                              void* d_out, int out_size, void* d_ws, size_t ws_size,
                              hipStream_t stream)
{
    (void)in_sizes; (void)n_in; (void)out_size;
    const float* hs  = (const float*)d_in[0];
    const float* gup = (const float*)d_in[1];
    const float* dwn = (const float*)d_in[2];
    float* out = (float*)d_out;

    const size_t SZ_HSB   = (size_t)TOKENS * HD * 2;          // 67.1 MB
    const size_t SZ_GUPT  = (size_t)2 * ID * HD * 2;          // 16.78 MB / expert
    const size_t SZ_DWNT  = (size_t)HD * ID * 2;              //  8.39 MB / expert
    const size_t SZ_GATED = (size_t)TPE * ID * 2;             // 16.78 MB / expert
    const size_t perExp   = SZ_GUPT + SZ_DWNT + SZ_GATED;     // 41.94 MB

    int G = (ws_size > SZ_HSB) ? (int)((ws_size - SZ_HSB) / perExp) : 1;
    if (G < 1) G = 1;
    if (G > NE) G = NE;

    unsigned short* hsB   = (unsigned short*)d_ws;
    unsigned short* gupT  = (unsigned short*)((char*)d_ws + SZ_HSB);
    unsigned short* dwnT  = (unsigned short*)((char*)d_ws + SZ_HSB + (size_t)G * SZ_GUPT);
    unsigned short* gated = (unsigned short*)((char*)d_ws + SZ_HSB + (size_t)G * (SZ_GUPT + SZ_DWNT));

    k_f2b<<<2048, 256, 0, stream>>>(hs, hsB, TOKENS * HD / 4);

    for (int e0 = 0; e0 < NE; e0 += G) {
        int ne = NE - e0;
        if (ne > G) ne = G;
        k_transpose<<<dim3((2 * ID) / 64, HD / 64, ne), 256, 0, stream>>>(gup, gupT, HD, 2 * ID, e0);
        k_transpose<<<dim3(HD / 64, ID / 64, ne), 256, 0, stream>>>(dwn, dwnT, ID, HD, e0);
        k_gemm1<<<dim3(ID / 128, TPE / 256, ne), 512, 0, stream>>>(hsB, gupT, gated, e0);
        k_gemm2<<<dim3(HD / 256, TPE / 256, ne), 512, 0, stream>>>(gated, dwnT, out, e0);
    }
}